// Round 6
// baseline (191.853 us; speedup 1.0000x reference)
//
#include <hip/hip_runtime.h>
#include <math.h>
#include <stdint.h>

#define DI __device__ __forceinline__

typedef __attribute__((ext_vector_type(8))) short bf16x8;
typedef __attribute__((ext_vector_type(4))) float f32x4;
typedef __attribute__((ext_vector_type(4))) int i32x4;

#define MFMA16(av, bv, acc) __builtin_amdgcn_mfma_f32_16x16x32_bf16(av, bv, acc, 0, 0, 0)

DI float elu_f(float v) { return v > 0.f ? v : expm1f(v); }

DI unsigned short f2bf(float f) {  // fp32 -> bf16 RNE
  uint32_t u = __float_as_uint(f);
  return (unsigned short)((u + 0x7FFFu + ((u >> 16) & 1u)) >> 16);
}

// ---------------- threefry2x32 (JAX, 20 rounds)
DI void threefry2x32(uint32_t k0, uint32_t k1, uint32_t& x0, uint32_t& x1) {
  uint32_t ks0 = k0, ks1 = k1, ks2 = k0 ^ k1 ^ 0x1BD11BDAu;
  x0 += ks0; x1 += ks1;
#define TFR(r) { x0 += x1; x1 = (x1 << r) | (x1 >> (32 - r)); x1 ^= x0; }
  TFR(13) TFR(15) TFR(26) TFR(6)   x0 += ks1; x1 += ks2 + 1u;
  TFR(17) TFR(29) TFR(16) TFR(24)  x0 += ks2; x1 += ks0 + 2u;
  TFR(13) TFR(15) TFR(26) TFR(6)   x0 += ks0; x1 += ks1 + 3u;
  TFR(17) TFR(29) TFR(16) TFR(24)  x0 += ks1; x1 += ks2 + 4u;
  TFR(13) TFR(15) TFR(26) TFR(6)   x0 += ks2; x1 += ks0 + 5u;
#undef TFR
}

DI float erfinv_f(float x) {  // Giles erfinv (rel err ~1e-6 << bf16 quantum)
  float w = -logf((1.0f - x) * (1.0f + x));
  float p;
  if (w < 5.0f) {
    w -= 2.5f;
    p = 2.81022636e-08f;
    p = fmaf(p, w, 3.43273939e-07f);
    p = fmaf(p, w, -3.5233877e-06f);
    p = fmaf(p, w, -4.39150654e-06f);
    p = fmaf(p, w, 0.00021858087f);
    p = fmaf(p, w, -0.00125372503f);
    p = fmaf(p, w, -0.00417768164f);
    p = fmaf(p, w, 0.246640727f);
    p = fmaf(p, w, 1.50140941f);
  } else {
    w = sqrtf(w) - 3.0f;
    p = -0.000200214257f;
    p = fmaf(p, w, 0.000100950558f);
    p = fmaf(p, w, 0.00134934322f);
    p = fmaf(p, w, -0.00367342844f);
    p = fmaf(p, w, 0.00573950773f);
    p = fmaf(p, w, -0.0076224613f);
    p = fmaf(p, w, 0.00943887047f);
    p = fmaf(p, w, 1.00167406f);
    p = fmaf(p, w, 2.83297682f);
  }
  return p * x;
}

struct MegaArgs {
  const float *x, *c;
  const float *fc1w, *fc1b, *fc2w, *fc2b, *muw, *mub, *lvw, *lvb;
  const float *g0w, *g0b, *g1w, *g1b, *g2w, *g2b;
  const float *w0, *b0, *w1, *b1, *w2, *b2;
  unsigned short *Ax, *Axh, *Axh2, *A0, *A1, *A2;
  unsigned short *fc1t, *fc2t, *mlvt, *g0t, *g1t, *w0b, *w1b, *w2b;
  float *cf, *outY, *outMu, *outLv;
};

// =====================================================================
// pipe32 — verbatim from the verified 175.6 µs kernel.
template <int KT, int NE, int D, bool ELU, bool OUTF32>
__global__ __launch_bounds__(128, 2)
void pipe32(const unsigned short* __restrict__ A,          // [2048][Kp]
            const unsigned short* __restrict__ Wt, int N,  // [NE][N][Kp]
            const float* __restrict__ bias,                // [NE][N]
            const float* __restrict__ cfp,                 // [2048][8] | null
            unsigned short* __restrict__ Cb, int ldcb, int cb_off,
            float* __restrict__ Cf) {
  constexpr int Kp = KT * 32, TT = NE * KT;
  __shared__ float bias_s[NE * 32];
  __shared__ float cfs[(NE > 1) ? 256 : 1];
  const int tid = threadIdx.x, lane = tid & 63, wv = tid >> 6;  // wv 0,1
  const int q = lane >> 4, l16 = lane & 15;
  const int m0 = blockIdx.x * 32;
  const int n0 = blockIdx.y * 32 + wv * 16;   // wave-private col slice
  const int gc = n0 + l16;
  const int wrow = (gc < N) ? gc : (N - 1);   // clamp: OOB lanes load junk, never stored
  const unsigned short* wlane = Wt + (size_t)wrow * Kp + q * 8;

  bf16x8 ring[D];
#pragma unroll
  for (int g = 0; g < D; g++) {
    if (g < TT) {
      int e = g / KT, c = g % KT;
      ring[g] = *(const bf16x8*)(wlane + (size_t)e * N * Kp + c * 32);
    }
  }
  bf16x8 areg[2][KT];
#pragma unroll
  for (int t = 0; t < 2; t++) {
    const unsigned short* alane = A + (size_t)(m0 + t * 16 + l16) * Kp + q * 8;
#pragma unroll
    for (int c = 0; c < KT; c++) areg[t][c] = *(const bf16x8*)(alane + c * 32);
  }

  if (NE == 1) {
    if (tid < 32) {
      int col = blockIdx.y * 32 + tid;
      bias_s[tid] = (col < N) ? bias[col] : 0.f;
    }
  } else {
    for (int idx = tid; idx < NE * 32; idx += 128) {
      int e = idx >> 5, col = blockIdx.y * 32 + (idx & 31);
      bias_s[idx] = (col < N) ? bias[(size_t)e * N + col] : 0.f;
    }
    for (int idx = tid; idx < 256; idx += 128)
      cfs[idx] = cfp[(size_t)(m0 + (idx >> 3)) * 8 + (idx & 7)];
  }
  __syncthreads();

  f32x4 acc[2] = {{0.f, 0.f, 0.f, 0.f}, {0.f, 0.f, 0.f, 0.f}};
  f32x4 accF[2] = {{0.f, 0.f, 0.f, 0.f}, {0.f, 0.f, 0.f, 0.f}};
#pragma unroll
  for (int g = 0; g < TT; g++) {
    const int e = g / KT, c = g % KT;
    bf16x8 bv = ring[g % D];
    acc[0] = MFMA16(areg[0][c], bv, acc[0]);
    acc[1] = MFMA16(areg[1][c], bv, acc[1]);
    if (g + D < TT) {
      int e2 = (g + D) / KT, c2 = (g + D) % KT;
      ring[g % D] = *(const bf16x8*)(wlane + (size_t)e2 * N * Kp + c2 * 32);
    }
    if (NE > 1 && c == KT - 1) {  // expert boundary: exact fp32 fold
      float bv2 = bias_s[e * 32 + wv * 16 + l16];
#pragma unroll
      for (int t = 0; t < 2; t++)
#pragma unroll
        for (int r = 0; r < 4; r++) {
          float ce = cfs[(t * 16 + q * 4 + r) * 8 + e];
          accF[t][r] += ce * (acc[t][r] + bv2);
          acc[t][r] = 0.f;
        }
    }
  }

  if (gc < N) {
#pragma unroll
    for (int t = 0; t < 2; t++)
#pragma unroll
      for (int r = 0; r < 4; r++) {
        int row = m0 + t * 16 + q * 4 + r;
        float v = (NE > 1) ? accF[t][r] : (acc[t][r] + bias_s[wv * 16 + l16]);
        if (ELU) v = elu_f(v);
        if (OUTF32) Cf[(size_t)row * 267 + gc] = v;
        else Cb[(size_t)row * ldcb + cb_off + gc] = f2bf(v);
      }
  }
}

// =====================================================================
// Expert-weight transpose riders (verbatim round-5, 128-thr variant).
DI void transpose_params(int t, const MegaArgs& a, const float*& W,
                         unsigned short*& D, int& K, int& N2, int& Kp2,
                         int& ldW, int& e, int& kt, int& nt) {
  if (t < 160)      { e = t / 20;  int lt = t % 20;  kt = lt / 4; nt = lt % 4; W = a.w0; D = a.w0b; K = 299; N2 = 256; Kp2 = 320; ldW = 256; }
  else if (t < 320) { int u = t - 160; e = u / 20; int lt = u % 20; kt = lt / 4; nt = lt % 4; W = a.w1; D = a.w1b; K = 288; N2 = 256; Kp2 = 288; ldW = 256; }
  else              { int u = t - 320; e = u / 25; int lt = u % 25; kt = lt / 5; nt = lt % 5; W = a.w2; D = a.w2b; K = 288; N2 = 267; Kp2 = 288; ldW = 267; }
}

DI void transpose128(unsigned short (*T)[72], int t, const MegaArgs& a) {
  const int tid = threadIdx.x;
  const float* W; unsigned short* D; int K, N2, Kp2, ldW, e, kt, nt;
  transpose_params(t, a, W, D, K, N2, Kp2, ldW, e, kt, nt);
  const int k0 = kt * 64, n0 = nt * 64;
  const float* We = W + (size_t)e * K * ldW;
  const int jj = tid & 63, ii0 = tid >> 6;  // 0..1
#pragma unroll
  for (int p = 0; p < 32; p++) {
    int i = ii0 + p * 2;
    int gk = k0 + i, gn = n0 + jj;
    float v = (gk < K && gn < N2) ? We[(size_t)gk * ldW + gn] : 0.f;
    T[jj][i] = f2bf(v);
  }
  __syncthreads();
  const int j0 = tid >> 2, chb = tid & 3;
#pragma unroll
  for (int jh = 0; jh < 2; jh++) {
    int j = j0 + jh * 32;
    int gn = n0 + j;
    if (gn < N2) {
      unsigned short* drow = D + ((size_t)e * N2 + gn) * Kp2 + k0;
#pragma unroll
      for (int s = 0; s < 2; s++) {
        int ch = chb + s * 4;
        if (k0 + ch * 8 < Kp2) {
          i32x4 v = *(i32x4*)(&T[j][ch * 8]);
          *(i32x4*)(drow + ch * 8) = v;
        }
      }
    }
  }
}

DI void conv128(const float* src, unsigned short* dst, int Ks, int Kp2) {
  for (int k = threadIdx.x; k < Kp2; k += 128)
    dst[k] = (k < Ks) ? f2bf(src[k]) : (unsigned short)0;
}

// =====================================================================
// D0: lean prep — activations (Ax, Axh/Axh2 x-part+pad, A0 c-part) +
// fc1t conversion. 768 blocks x 256 thr.
__global__ __launch_bounds__(256) void k_prep0(MegaArgs a) {
  const int bb = blockIdx.x, tid = threadIdx.x;
  if (bb < 512) {
    for (int rr = 0; rr < 4; rr++) {
      int b = bb * 4 + rr;
      const float* xr = a.x + (size_t)b * 267;
      const float* cr = a.c + (size_t)b * 267;
      unsigned short* axr = a.Ax + (size_t)b * 544;
      for (int k = tid; k < 544; k += 256) {
        float v = (k < 267) ? xr[k] : ((k < 534) ? cr[k - 267] : 0.f);
        axr[k] = f2bf(v);
      }
      unsigned short* ahr = a.Axh + (size_t)b * 544;
      unsigned short* ah2 = a.Axh2 + (size_t)b * 544;
      for (int k = tid; k < 267; k += 256) { unsigned short v = f2bf(xr[k]); ahr[k] = v; ah2[k] = v; }
      for (int k = 523 + tid; k < 544; k += 256) { ahr[k] = 0; ah2[k] = 0; }
      unsigned short* a0r = a.A0 + (size_t)b * 320;
      for (int k = tid; k < 288; k += 256)
        a0r[32 + k] = (k < 267) ? f2bf(cr[k]) : (unsigned short)0;
    }
  } else {
    int r = bb - 512;  // 0..255: fc1t rows
    const float* src = a.fc1w + (size_t)r * 534;
    unsigned short* dst = a.fc1t + (size_t)r * 544;
    for (int k = tid; k < 544; k += 256)
      dst[k] = (k < 534) ? f2bf(src[k]) : (unsigned short)0;
  }
}

// =====================================================================
// D1: fc1 GEMM (512 blocks, pipe32-identical math) + weight conversions
// (385) + w0 transposes (160). 1057 x 128 thr. (Round-5 verified.)
__global__ __launch_bounds__(128, 2) void k_fc1mix(MegaArgs a) {
  __shared__ float bias_s[32];
  __shared__ __align__(16) unsigned short T[64][72];
  const int bid = blockIdx.x, tid = threadIdx.x;
  if (bid < 512) {
    const int lane = tid & 63, wv = tid >> 6;
    const int q = lane >> 4, l16 = lane & 15;
    const int bx = bid & 63, by = bid >> 6;
    const int m0 = bx * 32;
    const int gc = by * 32 + wv * 16 + l16;  // < 256
    const unsigned short* wlane = a.fc1t + (size_t)gc * 544 + q * 8;

    bf16x8 ring[12];
#pragma unroll
    for (int g = 0; g < 12; g++)
      ring[g] = *(const bf16x8*)(wlane + g * 32);
    bf16x8 areg[2][17];
#pragma unroll
    for (int t = 0; t < 2; t++) {
      const unsigned short* alane = a.Ax + (size_t)(m0 + t * 16 + l16) * 544 + q * 8;
#pragma unroll
      for (int c = 0; c < 17; c++) areg[t][c] = *(const bf16x8*)(alane + c * 32);
    }
    if (tid < 32) bias_s[tid] = a.fc1b[by * 32 + tid];
    __syncthreads();

    f32x4 acc[2] = {{0.f, 0.f, 0.f, 0.f}, {0.f, 0.f, 0.f, 0.f}};
#pragma unroll
    for (int g = 0; g < 17; g++) {
      bf16x8 bv = ring[g % 12];
      acc[0] = MFMA16(areg[0][g], bv, acc[0]);
      acc[1] = MFMA16(areg[1][g], bv, acc[1]);
      if (g + 12 < 17)
        ring[g % 12] = *(const bf16x8*)(wlane + (g + 12) * 32);
    }
    float bc = bias_s[wv * 16 + l16];
#pragma unroll
    for (int t = 0; t < 2; t++)
#pragma unroll
      for (int r = 0; r < 4; r++) {
        int row = m0 + t * 16 + q * 4 + r;
        a.Axh[(size_t)row * 544 + 267 + gc] = f2bf(elu_f(acc[t][r] + bc));
      }
  } else if (bid < 897) {
    int c = bid - 512;
    if (c < 256)      conv128(a.fc2w + (size_t)c * 523, a.fc2t + (size_t)c * 544, 523, 544);
    else if (c < 320) { int n = c - 256;
                        conv128((n < 32) ? (a.muw + (size_t)n * 523) : (a.lvw + (size_t)(n - 32) * 523),
                                a.mlvt + (size_t)n * 544, 523, 544); }
    else if (c < 384) { int n = c - 320;
                        conv128(a.g0w + (size_t)n * 299, a.g0t + (size_t)n * 320, 299, 320); }
    else              conv128(a.g1w, a.g1t, 4096, 4096);
  } else {
    transpose128(T, bid - 897, a);  // t 0..159 -> w0
  }
}

// =====================================================================
// D2: fc2 GEMM (512 blocks, pipe32-identical math, Axh -> Axh2) +
// w1/w2 transposes (360 riders). 872 x 128 thr.
__global__ __launch_bounds__(128, 2) void k_fc2mix(MegaArgs a) {
  __shared__ float bias_s[32];
  __shared__ __align__(16) unsigned short T[64][72];
  const int bid = blockIdx.x, tid = threadIdx.x;
  if (bid < 512) {
    const int lane = tid & 63, wv = tid >> 6;
    const int q = lane >> 4, l16 = lane & 15;
    const int bx = bid & 63, by = bid >> 6;
    const int m0 = bx * 32;
    const int gc = by * 32 + wv * 16 + l16;  // < 256
    const unsigned short* wlane = a.fc2t + (size_t)gc * 544 + q * 8;

    bf16x8 ring[12];
#pragma unroll
    for (int g = 0; g < 12; g++)
      ring[g] = *(const bf16x8*)(wlane + g * 32);
    bf16x8 areg[2][17];
#pragma unroll
    for (int t = 0; t < 2; t++) {
      const unsigned short* alane = a.Axh + (size_t)(m0 + t * 16 + l16) * 544 + q * 8;
#pragma unroll
      for (int c = 0; c < 17; c++) areg[t][c] = *(const bf16x8*)(alane + c * 32);
    }
    if (tid < 32) bias_s[tid] = a.fc2b[by * 32 + tid];
    __syncthreads();

    f32x4 acc[2] = {{0.f, 0.f, 0.f, 0.f}, {0.f, 0.f, 0.f, 0.f}};
#pragma unroll
    for (int g = 0; g < 17; g++) {
      bf16x8 bv = ring[g % 12];
      acc[0] = MFMA16(areg[0][g], bv, acc[0]);
      acc[1] = MFMA16(areg[1][g], bv, acc[1]);
      if (g + 12 < 17)
        ring[g % 12] = *(const bf16x8*)(wlane + (g + 12) * 32);
    }
    float bc = bias_s[wv * 16 + l16];
#pragma unroll
    for (int t = 0; t < 2; t++)
#pragma unroll
      for (int r = 0; r < 4; r++) {
        int row = m0 + t * 16 + q * 4 + r;
        a.Axh2[(size_t)row * 544 + 267 + gc] = f2bf(elu_f(acc[t][r] + bc));
      }
  } else {
    transpose128(T, 160 + (bid - 512), a);  // t 160..519 -> w1, w2
  }
}

// =====================================================================
// D3: mu/lv GEMM + z + full gate stack — verbatim round-0 (256 thr, 128 blocks)
__global__ __launch_bounds__(256, 2) void k_mulv_gate(MegaArgs a) {
  __shared__ float mlvS[16 * 65];
  __shared__ __align__(16) unsigned short A0p[16 * 328];
  __shared__ __align__(16) unsigned short gaB[16 * 72];
  __shared__ __align__(16) unsigned short g1B[64 * 72];
  __shared__ float g2wT[64 * 8];
  __shared__ float gB[16 * 65];
  __shared__ float lg[16 * 8];
  const int tid = threadIdx.x, lane = tid & 63, wid = tid >> 6;
  const int q = lane >> 4, l16 = lane & 15;
  const int m0 = blockIdx.x * 16;
  const int cl = wid * 16 + l16;  // 0..63

  const unsigned short* alane = a.Axh2 + (size_t)(m0 + l16) * 544 + q * 8;
  const unsigned short* wlA = a.mlvt + (size_t)cl * 544 + q * 8;
  bf16x8 ring[8];
#pragma unroll
  for (int g = 0; g < 8; g++) ring[g] = *(const bf16x8*)(wlA + g * 32);
  bf16x8 areg[17];
#pragma unroll
  for (int c = 0; c < 17; c++) areg[c] = *(const bf16x8*)(alane + c * 32);
  f32x4 acc = {0.f, 0.f, 0.f, 0.f};
#pragma unroll
  for (int g = 0; g < 17; g++) {
    acc = MFMA16(areg[g], ring[g % 8], acc);
    if (g + 8 < 17) ring[g % 8] = *(const bf16x8*)(wlA + (g + 8) * 32);
  }
#pragma unroll
  for (int r = 0; r < 4; r++) mlvS[(q * 4 + r) * 65 + cl] = acc[r];
  for (int idx = tid; idx < 576; idx += 256) {
    int row = idx / 36, ch = 4 + idx % 36;
    *(i32x4*)(A0p + row * 328 + ch * 8) =
        *(const i32x4*)(a.A0 + (size_t)(m0 + row) * 320 + ch * 8);
  }
  if (tid < 16) { i32x4 z4 = {0, 0, 0, 0}; *(i32x4*)(A0p + tid * 328 + 320) = z4; }
  for (int idx = tid; idx < 512; idx += 256) {
    int row = idx >> 3, ch = idx & 7;
    *(i32x4*)(g1B + row * 72 + ch * 8) = *(const i32x4*)(a.g1t + (size_t)row * 64 + ch * 8);
  }
  for (int idx = tid; idx < 512; idx += 256)
    g2wT[(idx & 63) * 8 + (idx >> 6)] = a.g2w[idx];
  __syncthreads();

  {
    const int m = tid >> 4, j0 = (tid & 15) * 2, R = m0 + m;
#pragma unroll
    for (int jj = 0; jj < 2; jj++) {
      int j = j0 + jj;
      float mu = mlvS[m * 65 + j] + a.mub[j];
      float lvv = mlvS[m * 65 + j + 32] + a.lvb[j];
      uint32_t x0 = 0u, x1 = (uint32_t)(R * 32 + j);
      threefry2x32(0u, 42u, x0, x1);
      uint32_t bits = x0 ^ x1;
      float f = __uint_as_float((bits >> 9) | 0x3F800000u) - 1.0f;
      const float lo = -0.99999994039535522461f;
      float u = fmaf(f, 2.0f, lo);
      u = fmaxf(u, lo);
      float eps = 1.41421356237f * erfinv_f(u);
      float z = fmaf(eps, expf(0.5f * lvv), mu);
      a.outMu[(size_t)R * 32 + j] = mu;
      a.outLv[(size_t)R * 32 + j] = lvv;
      unsigned short zb = f2bf(z);
      A0p[m * 328 + j] = zb;
      a.A0[(size_t)R * 320 + j] = zb;
      a.A1[(size_t)R * 288 + j] = zb;
      a.A2[(size_t)R * 288 + j] = zb;
    }
  }
  __syncthreads();

  const unsigned short* wlC = a.g0t + (size_t)cl * 320 + q * 8;
  bf16x8 ring2[8];
#pragma unroll
  for (int g = 0; g < 8; g++) ring2[g] = *(const bf16x8*)(wlC + g * 32);
  f32x4 accC = {0.f, 0.f, 0.f, 0.f};
#pragma unroll
  for (int g = 0; g < 10; g++) {
    bf16x8 av = *(const bf16x8*)(A0p + l16 * 328 + g * 32 + q * 8);
    accC = MFMA16(av, ring2[g % 8], accC);
    if (g + 8 < 10) ring2[g % 8] = *(const bf16x8*)(wlC + (g + 8) * 32);
  }
  {
    float bc = a.g0b[cl];
#pragma unroll
    for (int r = 0; r < 4; r++)
      gaB[(q * 4 + r) * 72 + cl] = f2bf(elu_f(accC[r] + bc));
  }
  __syncthreads();

  f32x4 accD = {0.f, 0.f, 0.f, 0.f};
#pragma unroll
  for (int tau = 0; tau < 2; tau++) {
    bf16x8 av = *(const bf16x8*)(gaB + l16 * 72 + tau * 32 + q * 8);
    bf16x8 bv = *(const bf16x8*)(g1B + cl * 72 + tau * 32 + q * 8);
    accD = MFMA16(av, bv, accD);
  }
  {
    float bc = a.g1b[cl];
#pragma unroll
    for (int r = 0; r < 4; r++)
      gB[(q * 4 + r) * 65 + cl] = elu_f(accD[r] + bc);
  }
  __syncthreads();

  if (tid < 128) {
    int r = tid >> 3, e = tid & 7;
    float d = a.g2b[e];
#pragma unroll 8
    for (int k = 0; k < 64; k++) d = fmaf(gB[r * 65 + k], g2wT[k * 8 + e], d);
    lg[r * 8 + e] = d;
  }
  __syncthreads();
  if (tid < 16) {
    float mx = lg[tid * 8];
#pragma unroll
    for (int e2 = 1; e2 < 8; e2++) mx = fmaxf(mx, lg[tid * 8 + e2]);
    float s = 0.f, ex[8];
#pragma unroll
    for (int e2 = 0; e2 < 8; e2++) { ex[e2] = expf(lg[tid * 8 + e2] - mx); s += ex[e2]; }
    float inv = 1.f / s;
#pragma unroll
    for (int e2 = 0; e2 < 8; e2++) a.cf[(size_t)(m0 + tid) * 8 + e2] = ex[e2] * inv;
  }
}

// =====================================================================
extern "C" void kernel_launch(void* const* d_in, const int* in_sizes, int n_in,
                              void* d_out, int out_size, void* d_ws, size_t ws_size,
                              hipStream_t stream) {
  (void)in_sizes; (void)n_in; (void)out_size; (void)ws_size;
  float* out = (float*)d_out;
  float* ws = (float*)d_ws;

  MegaArgs a;
  a.x    = (const float*)d_in[0];
  a.c    = (const float*)d_in[1];
  a.fc1w = (const float*)d_in[2];  a.fc1b = (const float*)d_in[3];
  a.fc2w = (const float*)d_in[4];  a.fc2b = (const float*)d_in[5];
  a.muw  = (const float*)d_in[6];  a.mub  = (const float*)d_in[7];
  a.lvw  = (const float*)d_in[8];  a.lvb  = (const float*)d_in[9];
  a.g0w  = (const float*)d_in[10]; a.g0b  = (const float*)d_in[11];
  a.g1w  = (const float*)d_in[12]; a.g1b  = (const float*)d_in[13];
  a.g2w  = (const float*)d_in[14]; a.g2b  = (const float*)d_in[15];
  a.w0   = (const float*)d_in[16]; a.b0   = (const float*)d_in[17];
  a.w1   = (const float*)d_in[18]; a.b1   = (const float*)d_in[19];
  a.w2   = (const float*)d_in[20]; a.b2   = (const float*)d_in[21];

  a.outY  = out;
  a.outMu = out + 2048 * 267;
  a.outLv = a.outMu + 2048 * 32;

  a.Ax   = (unsigned short*)(ws);
  a.Axh  = (unsigned short*)(ws + 557056);
  a.Axh2 = (unsigned short*)(ws + 1114112);
  a.A0   = (unsigned short*)(ws + 1671168);
  a.A1   = (unsigned short*)(ws + 1998848);
  a.A2   = (unsigned short*)(ws + 2293760);
  a.fc1t = (unsigned short*)(ws + 2588672);
  a.fc2t = (unsigned short*)(ws + 2658304);
  a.mlvt = (unsigned short*)(ws + 2727936);
  a.g0t  = (unsigned short*)(ws + 2745344);
  a.g1t  = (unsigned short*)(ws + 2755584);
  a.w0b  = (unsigned short*)(ws + 2757632);
  a.w1b  = (unsigned short*)(ws + 3085312);
  a.w2b  = (unsigned short*)(ws + 3380224);
  a.cf   = ws + 3687808;

  k_prep0<<<768, 256, 0, stream>>>(a);
  k_fc1mix<<<1057, 128, 0, stream>>>(a);
  k_fc2mix<<<872, 128, 0, stream>>>(a);
  k_mulv_gate<<<128, 256, 0, stream>>>(a);
  pipe32<10, 8, 12, true, false><<<dim3(64, 8), 128, 0, stream>>>(
      a.A0, a.w0b, 256, a.b0, a.cf, a.A1, 288, 32, nullptr);
  pipe32<9, 8, 12, true, false><<<dim3(64, 8), 128, 0, stream>>>(
      a.A1, a.w1b, 256, a.b1, a.cf, a.A2, 288, 32, nullptr);
  pipe32<9, 8, 12, false, true><<<dim3(64, 9), 128, 0, stream>>>(
      a.A2, a.w2b, 267, a.b2, a.cf, nullptr, 0, 0, a.outY);
}

// Round 7
// 175.766 us; speedup vs baseline: 1.0915x; 1.0915x over previous
//
#include <hip/hip_runtime.h>
#include <math.h>
#include <stdint.h>

#define DI __device__ __forceinline__

typedef __attribute__((ext_vector_type(8))) short bf16x8;
typedef __attribute__((ext_vector_type(4))) float f32x4;
typedef __attribute__((ext_vector_type(4))) int i32x4;

DI float elu_f(float v) { return v > 0.f ? v : expm1f(v); }

DI unsigned short f2bf(float f) {  // fp32 -> bf16 RNE
  uint32_t u = __float_as_uint(f);
  return (unsigned short)((u + 0x7FFFu + ((u >> 16) & 1u)) >> 16);
}

// ---------------- threefry2x32 (JAX, 20 rounds)
DI void threefry2x32(uint32_t k0, uint32_t k1, uint32_t& x0, uint32_t& x1) {
  uint32_t ks0 = k0, ks1 = k1, ks2 = k0 ^ k1 ^ 0x1BD11BDAu;
  x0 += ks0; x1 += ks1;
#define TFR(r) { x0 += x1; x1 = (x1 << r) | (x1 >> (32 - r)); x1 ^= x0; }
  TFR(13) TFR(15) TFR(26) TFR(6)   x0 += ks1; x1 += ks2 + 1u;
  TFR(17) TFR(29) TFR(16) TFR(24)  x0 += ks2; x1 += ks0 + 2u;
  TFR(13) TFR(15) TFR(26) TFR(6)   x0 += ks0; x1 += ks1 + 3u;
  TFR(17) TFR(29) TFR(16) TFR(24)  x0 += ks1; x1 += ks2 + 4u;
  TFR(13) TFR(15) TFR(26) TFR(6)   x0 += ks2; x1 += ks0 + 5u;
#undef TFR
}

DI float erfinv_f(float x) {  // Giles erfinv (rel err ~1e-6 << bf16 quantum)
  float w = -logf((1.0f - x) * (1.0f + x));
  float p;
  if (w < 5.0f) {
    w -= 2.5f;
    p = 2.81022636e-08f;
    p = fmaf(p, w, 3.43273939e-07f);
    p = fmaf(p, w, -3.5233877e-06f);
    p = fmaf(p, w, -4.39150654e-06f);
    p = fmaf(p, w, 0.00021858087f);
    p = fmaf(p, w, -0.00125372503f);
    p = fmaf(p, w, -0.00417768164f);
    p = fmaf(p, w, 0.246640727f);
    p = fmaf(p, w, 1.50140941f);
  } else {
    w = sqrtf(w) - 3.0f;
    p = -0.000200214257f;
    p = fmaf(p, w, 0.000100950558f);
    p = fmaf(p, w, 0.00134934322f);
    p = fmaf(p, w, -0.00367342844f);
    p = fmaf(p, w, 0.00573950773f);
    p = fmaf(p, w, -0.0076224613f);
    p = fmaf(p, w, 0.00943887047f);
    p = fmaf(p, w, 1.00167406f);
    p = fmaf(p, w, 2.83297682f);
  }
  return p * x;
}

struct MegaArgs {
  const float *x, *c;
  const float *fc1w, *fc1b, *fc2w, *fc2b, *muw, *mub, *lvw, *lvb;
  const float *g0w, *g0b, *g1w, *g1b, *g2w, *g2b;
  const float *w0, *b0, *w1, *b1, *w2, *b2;
  unsigned short *Ax, *Axh, *Axh2, *A0, *A1, *A2;
  unsigned short *fc1t, *fc2t, *mlvt, *g0t, *g1t, *w0b, *w1b, *w2b;
  float *cf, *outY, *outMu, *outLv;
};

// =====================================================================
// pipe32: block = 32 rows x 32 cols, 128 thr = 2 waves SPLITTING COLUMNS.
// Verbatim round-0 structure; D is the W register-ring depth (load-use
// distance D iterations ~ D*16 cycles; D=16 for expert layers to cover
// L2 latency, D=12 for fc1/fc2 whose areg[2][17] is VGPR-heavy).
template <int KT, int NE, int D, bool ELU, bool OUTF32>
__global__ __launch_bounds__(128, 2)
void pipe32(const unsigned short* __restrict__ A,          // [2048][Kp]
            const unsigned short* __restrict__ Wt, int N,  // [NE][N][Kp]
            const float* __restrict__ bias,                // [NE][N]
            const float* __restrict__ cfp,                 // [2048][8] | null
            unsigned short* __restrict__ Cb, int ldcb, int cb_off,
            float* __restrict__ Cf) {
  constexpr int Kp = KT * 32, TT = NE * KT;
  __shared__ float bias_s[NE * 32];
  __shared__ float cfs[(NE > 1) ? 256 : 1];
  const int tid = threadIdx.x, lane = tid & 63, wv = tid >> 6;  // wv 0,1
  const int q = lane >> 4, l16 = lane & 15;
  const int m0 = blockIdx.x * 32;
  const int n0 = blockIdx.y * 32 + wv * 16;   // wave-private col slice
  const int gc = n0 + l16;
  const int wrow = (gc < N) ? gc : (N - 1);   // clamp: OOB lanes load junk, never stored
  const unsigned short* wlane = Wt + (size_t)wrow * Kp + q * 8;

  bf16x8 ring[D];
#pragma unroll
  for (int g = 0; g < D; g++) {
    if (g < TT) {
      int e = g / KT, c = g % KT;
      ring[g] = *(const bf16x8*)(wlane + (size_t)e * N * Kp + c * 32);
    }
  }
  bf16x8 areg[2][KT];
#pragma unroll
  for (int t = 0; t < 2; t++) {
    const unsigned short* alane = A + (size_t)(m0 + t * 16 + l16) * Kp + q * 8;
#pragma unroll
    for (int c = 0; c < KT; c++) areg[t][c] = *(const bf16x8*)(alane + c * 32);
  }

  if (NE == 1) {
    if (tid < 32) {
      int col = blockIdx.y * 32 + tid;
      bias_s[tid] = (col < N) ? bias[col] : 0.f;
    }
  } else {
    for (int idx = tid; idx < NE * 32; idx += 128) {
      int e = idx >> 5, col = blockIdx.y * 32 + (idx & 31);
      bias_s[idx] = (col < N) ? bias[(size_t)e * N + col] : 0.f;
    }
    for (int idx = tid; idx < 256; idx += 128)
      cfs[idx] = cfp[(size_t)(m0 + (idx >> 3)) * 8 + (idx & 7)];
  }
  __syncthreads();

  f32x4 acc[2] = {{0.f, 0.f, 0.f, 0.f}, {0.f, 0.f, 0.f, 0.f}};
  f32x4 accF[2] = {{0.f, 0.f, 0.f, 0.f}, {0.f, 0.f, 0.f, 0.f}};
#pragma unroll
  for (int g = 0; g < TT; g++) {
    const int e = g / KT, c = g % KT;
    bf16x8 bv = ring[g % D];
    acc[0] = __builtin_amdgcn_mfma_f32_16x16x32_bf16(areg[0][c], bv, acc[0], 0, 0, 0);
    acc[1] = __builtin_amdgcn_mfma_f32_16x16x32_bf16(areg[1][c], bv, acc[1], 0, 0, 0);
    if (g + D < TT) {
      int e2 = (g + D) / KT, c2 = (g + D) % KT;
      ring[g % D] = *(const bf16x8*)(wlane + (size_t)e2 * N * Kp + c2 * 32);
    }
    if (NE > 1 && c == KT - 1) {  // expert boundary: exact fp32 fold
      float bv2 = bias_s[e * 32 + wv * 16 + l16];
#pragma unroll
      for (int t = 0; t < 2; t++)
#pragma unroll
        for (int r = 0; r < 4; r++) {
          float ce = cfs[(t * 16 + q * 4 + r) * 8 + e];
          accF[t][r] += ce * (acc[t][r] + bv2);
          acc[t][r] = 0.f;
        }
    }
  }

  if (gc < N) {
#pragma unroll
    for (int t = 0; t < 2; t++)
#pragma unroll
      for (int r = 0; r < 4; r++) {
        int row = m0 + t * 16 + q * 4 + r;
        float v = (NE > 1) ? accF[t][r] : (acc[t][r] + bias_s[wv * 16 + l16]);
        if (ELU) v = elu_f(v);
        if (OUTF32) Cf[(size_t)row * 267 + gc] = v;
        else Cb[(size_t)row * ldcb + cb_off + gc] = f2bf(v);
      }
  }
}

// =====================================================================
// prep (one dispatch, 1673 blocks x 256 thr) — verbatim round-0
__global__ __launch_bounds__(256) void k_prep(MegaArgs a) {
  __shared__ __align__(16) unsigned short T[64][72];
  const int bb = blockIdx.x, tid = threadIdx.x;
  if (bb < 512) {
    for (int rr = 0; rr < 4; rr++) {
      int b = bb * 4 + rr;
      const float* xr = a.x + (size_t)b * 267;
      const float* cr = a.c + (size_t)b * 267;
      unsigned short* axr = a.Ax + (size_t)b * 544;
      for (int k = tid; k < 544; k += 256) {
        float v = (k < 267) ? xr[k] : ((k < 534) ? cr[k - 267] : 0.f);
        axr[k] = f2bf(v);
      }
      unsigned short* ahr = a.Axh + (size_t)b * 544;
      unsigned short* ah2 = a.Axh2 + (size_t)b * 544;
      for (int k = tid; k < 267; k += 256) { unsigned short v = f2bf(xr[k]); ahr[k] = v; ah2[k] = v; }
      for (int k = 523 + tid; k < 544; k += 256) { ahr[k] = 0; ah2[k] = 0; }
      unsigned short* a0r = a.A0 + (size_t)b * 320;
      for (int k = tid; k < 288; k += 256)
        a0r[32 + k] = (k < 267) ? f2bf(cr[k]) : (unsigned short)0;
    }
  } else if (bb < 1152) {
    int r = bb - 512;
    const float* src; unsigned short* dst; int Ks, Kp2;
    if (r < 256)      { src = a.fc1w + (size_t)r * 534; dst = a.fc1t + (size_t)r * 544; Ks = 534; Kp2 = 544; }
    else if (r < 512) { int n = r - 256; src = a.fc2w + (size_t)n * 523; dst = a.fc2t + (size_t)n * 544; Ks = 523; Kp2 = 544; }
    else if (r < 576) { int n = r - 512; src = (n < 32) ? (a.muw + (size_t)n * 523) : (a.lvw + (size_t)(n - 32) * 523);
                        dst = a.mlvt + (size_t)n * 544; Ks = 523; Kp2 = 544; }
    else              { int n = r - 576; src = a.g0w + (size_t)n * 299; dst = a.g0t + (size_t)n * 320; Ks = 299; Kp2 = 320; }
    for (int k = tid; k < Kp2; k += 256) dst[k] = (k < Ks) ? f2bf(src[k]) : (unsigned short)0;
  } else if (bb == 1152) {
    for (int k = tid; k < 4096; k += 256) a.g1t[k] = f2bf(a.g1w[k]);
  } else {
    int t = bb - 1153;
    const float* W; unsigned short* D; int K, N2, Kp2, ldW, e, kt, nt;
    if (t < 160)      { e = t / 20;  int lt = t % 20;  kt = lt / 4; nt = lt % 4; W = a.w0; D = a.w0b; K = 299; N2 = 256; Kp2 = 320; ldW = 256; }
    else if (t < 320) { int u = t - 160; e = u / 20; int lt = u % 20; kt = lt / 4; nt = lt % 4; W = a.w1; D = a.w1b; K = 288; N2 = 256; Kp2 = 288; ldW = 256; }
    else              { int u = t - 320; e = u / 25; int lt = u % 25; kt = lt / 5; nt = lt % 5; W = a.w2; D = a.w2b; K = 288; N2 = 267; Kp2 = 288; ldW = 267; }
    const int k0 = kt * 64, n0 = nt * 64;
    const float* We = W + (size_t)e * K * ldW;
    const int jj = tid & 63, ii0 = tid >> 6;
#pragma unroll
    for (int p = 0; p < 16; p++) {
      int i = ii0 + p * 4;
      int gk = k0 + i, gn = n0 + jj;
      float v = (gk < K && gn < N2) ? We[(size_t)gk * ldW + gn] : 0.f;
      T[jj][i] = f2bf(v);
    }
    __syncthreads();
    int j = tid >> 2, chb = tid & 3;
    int gn = n0 + j;
    if (gn < N2) {
      unsigned short* drow = D + ((size_t)e * N2 + gn) * Kp2 + k0;
#pragma unroll
      for (int s = 0; s < 2; s++) {
        int ch = chb + s * 4;
        if (k0 + ch * 8 < Kp2) {
          i32x4 v = *(i32x4*)(&T[j][ch * 8]);
          *(i32x4*)(drow + ch * 8) = v;
        }
      }
    }
  }
}

// =====================================================================
// mu/lv GEMM + z + full gate stack — verbatim round-0 (256 thr, 128 blocks)
__global__ __launch_bounds__(256, 2) void k_mulv_gate(MegaArgs a) {
  __shared__ float mlvS[16 * 65];
  __shared__ __align__(16) unsigned short A0p[16 * 328];
  __shared__ __align__(16) unsigned short gaB[16 * 72];
  __shared__ __align__(16) unsigned short g1B[64 * 72];
  __shared__ float g2wT[64 * 8];
  __shared__ float gB[16 * 65];
  __shared__ float lg[16 * 8];
  const int tid = threadIdx.x, lane = tid & 63, wid = tid >> 6;
  const int q = lane >> 4, l16 = lane & 15;
  const int m0 = blockIdx.x * 16;
  const int cl = wid * 16 + l16;  // 0..63

  const unsigned short* alane = a.Axh2 + (size_t)(m0 + l16) * 544 + q * 8;
  const unsigned short* wlA = a.mlvt + (size_t)cl * 544 + q * 8;
  bf16x8 ring[8];
#pragma unroll
  for (int g = 0; g < 8; g++) ring[g] = *(const bf16x8*)(wlA + g * 32);
  bf16x8 areg[17];
#pragma unroll
  for (int c = 0; c < 17; c++) areg[c] = *(const bf16x8*)(alane + c * 32);
  f32x4 acc = {0.f, 0.f, 0.f, 0.f};
#pragma unroll
  for (int g = 0; g < 17; g++) {
    acc = __builtin_amdgcn_mfma_f32_16x16x32_bf16(areg[g], ring[g % 8], acc, 0, 0, 0);
    if (g + 8 < 17) ring[g % 8] = *(const bf16x8*)(wlA + (g + 8) * 32);
  }
#pragma unroll
  for (int r = 0; r < 4; r++) mlvS[(q * 4 + r) * 65 + cl] = acc[r];
  for (int idx = tid; idx < 576; idx += 256) {
    int row = idx / 36, ch = 4 + idx % 36;
    *(i32x4*)(A0p + row * 328 + ch * 8) =
        *(const i32x4*)(a.A0 + (size_t)(m0 + row) * 320 + ch * 8);
  }
  if (tid < 16) { i32x4 z4 = {0, 0, 0, 0}; *(i32x4*)(A0p + tid * 328 + 320) = z4; }
  for (int idx = tid; idx < 512; idx += 256) {
    int row = idx >> 3, ch = idx & 7;
    *(i32x4*)(g1B + row * 72 + ch * 8) = *(const i32x4*)(a.g1t + (size_t)row * 64 + ch * 8);
  }
  for (int idx = tid; idx < 512; idx += 256)
    g2wT[(idx & 63) * 8 + (idx >> 6)] = a.g2w[idx];
  __syncthreads();

  {
    const int m = tid >> 4, j0 = (tid & 15) * 2, R = m0 + m;
#pragma unroll
    for (int jj = 0; jj < 2; jj++) {
      int j = j0 + jj;
      float mu = mlvS[m * 65 + j] + a.mub[j];
      float lvv = mlvS[m * 65 + j + 32] + a.lvb[j];
      uint32_t x0 = 0u, x1 = (uint32_t)(R * 32 + j);
      threefry2x32(0u, 42u, x0, x1);
      uint32_t bits = x0 ^ x1;
      float f = __uint_as_float((bits >> 9) | 0x3F800000u) - 1.0f;
      const float lo = -0.99999994039535522461f;
      float u = fmaf(f, 2.0f, lo);
      u = fmaxf(u, lo);
      float eps = 1.41421356237f * erfinv_f(u);
      float z = fmaf(eps, expf(0.5f * lvv), mu);
      a.outMu[(size_t)R * 32 + j] = mu;
      a.outLv[(size_t)R * 32 + j] = lvv;
      unsigned short zb = f2bf(z);
      A0p[m * 328 + j] = zb;
      a.A0[(size_t)R * 320 + j] = zb;
      a.A1[(size_t)R * 288 + j] = zb;
      a.A2[(size_t)R * 288 + j] = zb;
    }
  }
  __syncthreads();

  const unsigned short* wlC = a.g0t + (size_t)cl * 320 + q * 8;
  bf16x8 ring2[8];
#pragma unroll
  for (int g = 0; g < 8; g++) ring2[g] = *(const bf16x8*)(wlC + g * 32);
  f32x4 accC = {0.f, 0.f, 0.f, 0.f};
#pragma unroll
  for (int g = 0; g < 10; g++) {
    bf16x8 av = *(const bf16x8*)(A0p + l16 * 328 + g * 32 + q * 8);
    accC = __builtin_amdgcn_mfma_f32_16x16x32_bf16(av, ring2[g % 8], accC, 0, 0, 0);
    if (g + 8 < 10) ring2[g % 8] = *(const bf16x8*)(wlC + (g + 8) * 32);
  }
  {
    float bc = a.g0b[cl];
#pragma unroll
    for (int r = 0; r < 4; r++)
      gaB[(q * 4 + r) * 72 + cl] = f2bf(elu_f(accC[r] + bc));
  }
  __syncthreads();

  f32x4 accD = {0.f, 0.f, 0.f, 0.f};
#pragma unroll
  for (int tau = 0; tau < 2; tau++) {
    bf16x8 av = *(const bf16x8*)(gaB + l16 * 72 + tau * 32 + q * 8);
    bf16x8 bv = *(const bf16x8*)(g1B + cl * 72 + tau * 32 + q * 8);
    accD = __builtin_amdgcn_mfma_f32_16x16x32_bf16(av, bv, accD, 0, 0, 0);
  }
  {
    float bc = a.g1b[cl];
#pragma unroll
    for (int r = 0; r < 4; r++)
      gB[(q * 4 + r) * 65 + cl] = elu_f(accD[r] + bc);
  }
  __syncthreads();

  if (tid < 128) {
    int r = tid >> 3, e = tid & 7;
    float d = a.g2b[e];
#pragma unroll 8
    for (int k = 0; k < 64; k++) d = fmaf(gB[r * 65 + k], g2wT[k * 8 + e], d);
    lg[r * 8 + e] = d;
  }
  __syncthreads();
  if (tid < 16) {
    float mx = lg[tid * 8];
#pragma unroll
    for (int e2 = 1; e2 < 8; e2++) mx = fmaxf(mx, lg[tid * 8 + e2]);
    float s = 0.f, ex[8];
#pragma unroll
    for (int e2 = 0; e2 < 8; e2++) { ex[e2] = expf(lg[tid * 8 + e2] - mx); s += ex[e2]; }
    float inv = 1.f / s;
#pragma unroll
    for (int e2 = 0; e2 < 8; e2++) a.cf[(size_t)(m0 + tid) * 8 + e2] = ex[e2] * inv;
  }
}

// =====================================================================
extern "C" void kernel_launch(void* const* d_in, const int* in_sizes, int n_in,
                              void* d_out, int out_size, void* d_ws, size_t ws_size,
                              hipStream_t stream) {
  (void)in_sizes; (void)n_in; (void)out_size; (void)ws_size;
  float* out = (float*)d_out;
  float* ws = (float*)d_ws;

  MegaArgs a;
  a.x    = (const float*)d_in[0];
  a.c    = (const float*)d_in[1];
  a.fc1w = (const float*)d_in[2];  a.fc1b = (const float*)d_in[3];
  a.fc2w = (const float*)d_in[4];  a.fc2b = (const float*)d_in[5];
  a.muw  = (const float*)d_in[6];  a.mub  = (const float*)d_in[7];
  a.lvw  = (const float*)d_in[8];  a.lvb  = (const float*)d_in[9];
  a.g0w  = (const float*)d_in[10]; a.g0b  = (const float*)d_in[11];
  a.g1w  = (const float*)d_in[12]; a.g1b  = (const float*)d_in[13];
  a.g2w  = (const float*)d_in[14]; a.g2b  = (const float*)d_in[15];
  a.w0   = (const float*)d_in[16]; a.b0   = (const float*)d_in[17];
  a.w1   = (const float*)d_in[18]; a.b1   = (const float*)d_in[19];
  a.w2   = (const float*)d_in[20]; a.b2   = (const float*)d_in[21];

  a.outY  = out;
  a.outMu = out + 2048 * 267;
  a.outLv = a.outMu + 2048 * 32;

  a.Ax   = (unsigned short*)(ws);
  a.Axh  = (unsigned short*)(ws + 557056);
  a.Axh2 = (unsigned short*)(ws + 1114112);
  a.A0   = (unsigned short*)(ws + 1671168);
  a.A1   = (unsigned short*)(ws + 1998848);
  a.A2   = (unsigned short*)(ws + 2293760);
  a.fc1t = (unsigned short*)(ws + 2588672);
  a.fc2t = (unsigned short*)(ws + 2658304);
  a.mlvt = (unsigned short*)(ws + 2727936);
  a.g0t  = (unsigned short*)(ws + 2745344);
  a.g1t  = (unsigned short*)(ws + 2755584);
  a.w0b  = (unsigned short*)(ws + 2757632);
  a.w1b  = (unsigned short*)(ws + 3085312);
  a.w2b  = (unsigned short*)(ws + 3380224);
  a.cf   = ws + 3687808;

  dim3 blkP(256), blkG(128);
  k_prep<<<1673, blkP, 0, stream>>>(a);
  pipe32<17, 1, 12, true, false><<<dim3(64, 8), blkG, 0, stream>>>(
      a.Ax, a.fc1t, 256, a.fc1b, nullptr, a.Axh, 544, 267, nullptr);
  pipe32<17, 1, 12, true, false><<<dim3(64, 8), blkG, 0, stream>>>(
      a.Axh, a.fc2t, 256, a.fc2b, nullptr, a.Axh2, 544, 267, nullptr);
  k_mulv_gate<<<128, blkP, 0, stream>>>(a);
  pipe32<10, 8, 16, true, false><<<dim3(64, 8), blkG, 0, stream>>>(
      a.A0, a.w0b, 256, a.b0, a.cf, a.A1, 288, 32, nullptr);
  pipe32<9, 8, 16, true, false><<<dim3(64, 8), blkG, 0, stream>>>(
      a.A1, a.w1b, 256, a.b1, a.cf, a.A2, 288, 32, nullptr);
  pipe32<9, 8, 16, false, true><<<dim3(64, 9), blkG, 0, stream>>>(
      a.A2, a.w2b, 267, a.b2, a.cf, nullptr, 0, 0, a.outY);
}